// Round 4
// baseline (209.159 us; speedup 1.0000x reference)
//
#include <hip/hip_runtime.h>
#include <math.h>

#define NB 4
#define C_IN 256
#define CKC 64
#define HWSZ 4096   // 64*64
#define K2 25
#define NOC2 40     // 33 output chans padded to 40 (8 groups x 5)

// workspace layout (float offsets)
#define WS_CX    0
#define WS_OFF   (WS_CX + NB*CKC*HWSZ)          // 1048576
#define WS_MASK  (WS_OFF + NB*8*HWSZ)           // +131072
#define WS_WT    (WS_MASK + NB*K2*HWSZ)         // +409600
// wcT (16384 floats) overlays WS_MASK: dead until k_convsm writes maskb,
// and k_compress (its only reader) runs before k_convsm.

#define NWT (CKC * 9 * NOC2)    // 23040
#define NWC (C_IN * CKC)        // 16384

// ---------------- Kernel D: weight prep ----------------
// wT[c][tap][oc(40)] for the 3x3 convs; wcT[c][ck] for the compressor.
__global__ void k_wt(const float* __restrict__ wk, const float* __restrict__ wo,
                     const float* __restrict__ wc,
                     float* __restrict__ wT, float* __restrict__ wcT) {
  int i = blockIdx.x * 256 + threadIdx.x;
  if (i < NWT) {
    int oc = i % NOC2;
    int r = i / NOC2;        // r = c*9 + tap
    int tap = r % 9, c = r / 9;
    float v = 0.f;
    if (oc < 8)       v = wo[(oc * CKC + c) * 9 + tap];
    else if (oc < 33) v = wk[((oc - 8) * CKC + c) * 9 + tap];
    wT[i] = v;
  } else {
    int j = i - NWT;
    if (j < NWC) {
      int c = j >> 6, ck = j & 63;
      wcT[j] = wc[ck * C_IN + c];
    }
  }
}

// ---------------- Kernel A (v2): 1x1 compressor as LDS-tiled GEMM ----------
// 256 blocks x 512 thr; block = one 64-pixel row, 8 waves = 8 ck-groups of 8.
// x staged in LDS 64c-chunks; weights via wave-uniform s_load from wcT.
__global__ __launch_bounds__(512) void k_compress(const float* __restrict__ x,
    const float* __restrict__ wcT, const float* __restrict__ bc,
    float* __restrict__ cx) {
  __shared__ float s_x[64 * 64];   // [c][pos] 16KB
  int t = threadIdx.x;
  int pos0 = blockIdx.x * 64;
  int n = pos0 >> 12, hw0 = pos0 & 4095;
  int p = t & 63;
  int g = __builtin_amdgcn_readfirstlane(t >> 6);   // ck-group 0..7, wave-uniform
  const float* xn = x + (size_t)n * (C_IN * HWSZ) + hw0;
  float acc[8];
  #pragma unroll
  for (int i = 0; i < 8; i++) acc[i] = bc[g * 8 + i];
  for (int cc = 0; cc < 4; cc++) {
    __syncthreads();
    #pragma unroll
    for (int it = 0; it < 8; it++) {
      int idx = t + it * 512;
      int c = idx >> 6, pp = idx & 63;
      s_x[idx] = xn[(cc * 64 + c) * HWSZ + pp];
    }
    __syncthreads();
    const float* wbase = wcT + (cc * 64) * 64 + g * 8;
    #pragma unroll 4
    for (int c = 0; c < 64; c++) {
      float v = s_x[c * 64 + p];
      const float* w = wbase + c * 64;
      #pragma unroll
      for (int i = 0; i < 8; i++) acc[i] += v * w[i];
    }
  }
  float* o = cx + (size_t)n * (CKC * HWSZ) + hw0 + p;
  #pragma unroll
  for (int i = 0; i < 8; i++) o[(g * 8 + i) * HWSZ] = acc[i];
}

// ---------------- Kernel B (v3): fused 3x3 convs + softmax ----------------
// grid (64,4) x 512 thr: block = one 16x4 spatial tile; 64 px x 8 oc-groups
// of 5 (NOC2=40). 2 waves/SIMD for latency hiding.
__global__ __launch_bounds__(512) void k_convsm(const float* __restrict__ cx,
    const float* __restrict__ wT, const float* __restrict__ bk, const float* __restrict__ bo,
    float* __restrict__ offb, float* __restrict__ maskb) {
  __shared__ float s_tile[64 * 108];   // 64 c x (6 rows x 18 cols) halo tile
  __shared__ float s_res[NOC2 * 64];   // [oc][px]
  int t = threadIdx.x;
  int n = blockIdx.y;
  int tile = blockIdx.x;
  int x0 = (tile & 3) * 16, y0 = (tile >> 2) * 4;
  const float* cxn = cx + n * (CKC * HWSZ);

  // stage cx halo tile (zero-padded)
  for (int idx = t; idx < 6912; idx += 512) {
    int c = idx / 108;
    int rem = idx - c * 108;
    int row = rem / 18, col = rem - row * 18;
    int gy = y0 - 1 + row, gx = x0 - 1 + col;
    float v = 0.f;
    if ((unsigned)gy < 64u && (unsigned)gx < 64u) v = cxn[c * HWSZ + gy * 64 + gx];
    s_tile[idx] = v;
  }
  __syncthreads();

  int p = t & 63;
  int px = p & 15, py = p >> 4;
  int g = __builtin_amdgcn_readfirstlane(t >> 6);   // oc-group 0..7, wave-uniform
  float acc[5];
  #pragma unroll
  for (int j = 0; j < 5; j++) acc[j] = 0.f;
  const float* wg = wT + g * 5;
  for (int c = 0; c < CKC; c++) {
    const float* tl = s_tile + c * 108 + py * 18 + px;
    const float* wc9 = wg + c * 9 * NOC2;
    #pragma unroll
    for (int tap = 0; tap < 9; tap++) {
      int dy = tap / 3, dx = tap % 3;
      float v = tl[dy * 18 + dx];
      const float* w = wc9 + tap * NOC2;
      #pragma unroll
      for (int j = 0; j < 5; j++) acc[j] += v * w[j];
    }
  }
  #pragma unroll
  for (int j = 0; j < 5; j++) s_res[(g * 5 + j) * 64 + p] = acc[j];
  __syncthreads();

  int hw = (y0 + py) * 64 + x0 + px;
  // offsets: 8 channels; group g writes oc = g (row index == oc)
  offb[(n * 8 + g) * HWSZ + hw] = s_res[g * 64 + p] + bo[g];
  // softmax over 25 kernel positions: threads 0..63, one pixel per lane
  if (t < 64) {
    float m[25], mx = -1e30f;
    #pragma unroll
    for (int k = 0; k < 25; k++) { m[k] = s_res[(8 + k) * 64 + p] + bk[k]; mx = fmaxf(mx, m[k]); }
    float s = 0.f;
    #pragma unroll
    for (int k = 0; k < 25; k++) { m[k] = __expf(m[k] - mx); s += m[k]; }
    float inv = 1.f / s;
    #pragma unroll
    for (int k = 0; k < 25; k++) maskb[(n * 25 + k) * HWSZ + hw] = m[k] * inv;
  }
}

// ---------------- Kernel C (v5): main CARAFE reassembly ----------------
// 1024 blocks x 256 thr = 4 blocks/CU (LDS 38.5KB). Block = (n, a, wq, c-half).
// v3: hoisted staging descriptors + register prefetch of next chunk (T14).
// v4: capacity-driven XCD swizzle (xcd = n*2+half): per-XCD read set 2.1MB x
//     + 0.4MB maskb fits the private 4MB L2 -> FETCH 66->30.7MB (verified r3).
// v5: REVERT nontemporal stores (r3 regression: nt bypasses L2, so the
//     vmcnt(0) drain before each of the 16 chunk-loop barriers waits on
//     HBM-latency store completion instead of ~200cy L2 absorb; ~+5us).
//     Plus phase-1 tap-split: the ~100 scattered maskb gathers/thread ran on
//     threads 0..127 while 128..255 idled; split 25 taps into halves (0..12 /
//     12..24, overlap writes identical value -> benign) across all 256 thr.
__global__ __launch_bounds__(256, 4) void k_carafe(const float* __restrict__ x,
    const float* __restrict__ offb, const float* __restrict__ maskb,
    float* __restrict__ out) {
  __attribute__((aligned(16))) __shared__ float s_patch[32 * 201]; // 25728B; aliased as s_out [32][130]
  __attribute__((aligned(16))) __shared__ float s_kern[32 * 25 * 4]; // 12800B
  int t = threadIdx.x;
  int b = blockIdx.x;
  // XCD-aware decode: consecutive blockIdx round-robin across 8 XCDs, so
  // bits [2:0] select the XCD -> pin (n, half) per XCD; order rest by (aa,wq)
  // so row-halo-sharing aa-neighbors are temporally adjacent on one XCD.
  int xcd = b & 7;
  int q = b >> 3;          // 0..127
  int n = xcd >> 1;
  int half = xcd & 1;
  int aa = q >> 2;         // 0..31
  int wq = q & 3;
  int a = aa + (aa & 16);                 // h base: bit4 == 0
  int yout = (a & 15) * 8 + wq * 2 + ((a >> 5) & 1);
  int w0 = wq * 16;
  int cbase = n * C_IN + half * 128;

  // ---- hoisted staging descriptors (computed ONCE, not per cc chunk) ----
  // element it handled by this thread: idx = t + it*256 over 6400 = 32c x 200
  // dst in s_patch = c*201 + rem = idx + c  -> only c (5 bits) needs storing.
  int srcOff[25];          // channel-plane-relative source offset (0 if OOB)
  unsigned cpack[5] = {0, 0, 0, 0, 0};   // 25 x 5-bit c values, 6 per word
  unsigned vbits = 0;      // validity bitmask
  #pragma unroll
  for (int it = 0; it < 25; it++) {
    int idx = t + it * 256;
    int c = idx / 200;
    int rem = idx - c * 200;
    int rg = rem / 20;
    int col = rem - rg * 20;
    int row = (rg < 5) ? (a - 2 + rg) : (a + 9 + rg);
    int gc = w0 - 2 + col;
    bool ok = ((unsigned)row < 64u) & ((unsigned)gc < 64u);
    srcOff[it] = ok ? (c * HWSZ + row * 64 + gc) : 0;
    vbits |= (ok ? 1u : 0u) << it;
    cpack[it / 6] |= (unsigned)c << ((it % 6) * 5);
  }

  // prefetch chunk 0 into registers (flies during phase 1)
  float rv[25];
  {
    const float* xn = x + (size_t)cbase * HWSZ;
    #pragma unroll
    for (int it = 0; it < 25; it++) rv[it] = xn[srcOff[it]];
  }

  // Phase 1: per-(pos,u) 25 resampled kernel weights -> LDS [p][tap][u]
  // All 256 threads: (p,u) pair + tap-half. kh=0 -> taps 0..12, kh=1 ->
  // taps 12..24 (k=12 written twice with identical value -> benign).
  {
    int p = t >> 3;          // 0..31
    int u = (t >> 1) & 3;    // 0..3
    int kh = t & 1;          // tap half
    int hb = p >> 4, wl = p & 15;
    int h = a + hb * 16;
    int wcol = w0 + wl;
    float ox = offb[(n * 8 + u) * HWSZ + h * 64 + wcol];
    float oy = offb[(n * 8 + 4 + u) * HWSZ + h * 64 + wcol];
    float gx = fminf(fmaxf((float)wcol + ox, 0.f), 63.f);
    float gy = fminf(fmaxf((float)h + oy, 0.f), 63.f);
    float fx0 = floorf(gx), fy0 = floorf(gy);
    int x0 = (int)fx0, y0 = (int)fy0;
    float fx = gx - fx0, fy = gy - fy0;
    int x1 = min(x0 + 1, 63), y1 = min(y0 + 1, 63);
    float w11 = fx * fy;
    float w10 = fy - w11, w01 = fx - w11, w00 = 1.f - fx - fy + w11;
    const float* mb = maskb + n * (K2 * HWSZ);
    int i00 = y0 * 64 + x0, i01 = y0 * 64 + x1;
    int i10 = y1 * 64 + x0, i11 = y1 * 64 + x1;
    int kb = kh * 12;
    #pragma unroll 13
    for (int kk = 0; kk < 13; kk++) {
      int k = kb + kk;
      const float* mk = mb + k * HWSZ;
      float v = w00 * mk[i00] + w01 * mk[i01] + w10 * mk[i10] + w11 * mk[i11];
      s_kern[(p * 25 + k) * 4 + u] = v;
    }
  }

  int cl = t & 31, g = t >> 5;            // channel lane 0..31, pos-group 0..7
  int hb = g >> 2, wl0 = (g & 3) * 4;     // each group: 4 consecutive wl in one hb
  float* s_out = s_patch;                 // alias: [32][130] = 16640B <= 25728B

  for (int cc = 0; cc < 4; cc++) {
    __syncthreads();   // covers phase-1 (first iter) and staging-vs-store alias (later)
    // stage x patch from prefetched registers: 32 c x 10 rows x 20 cols
    #pragma unroll
    for (int it = 0; it < 25; it++) {
      int c = (cpack[it / 6] >> ((it % 6) * 5)) & 31;
      float v = (vbits & (1u << it)) ? rv[it] : 0.f;
      s_patch[t + it * 256 + c] = v;       // == c*201 + rem
    }
    __syncthreads();
    // issue next chunk's loads NOW; latency hides under compute+store below
    if (cc < 3) {
      const float* xn = x + (size_t)(cbase + (cc + 1) * 32) * HWSZ;
      #pragma unroll
      for (int it = 0; it < 25; it++) rv[it] = xn[srcOff[it]];
    }
    // compute: thread (cl, g) -> 4 positions x 4 u; register row-cache over dy
    float acc[4][4];
    #pragma unroll
    for (int i = 0; i < 4; i++)
      acc[i][0] = acc[i][1] = acc[i][2] = acc[i][3] = 0.f;
    const float* pc = s_patch + cl * 201 + hb * 100 + wl0;
    #pragma unroll
    for (int dy = 0; dy < 5; dy++) {
      float r8[8];
      #pragma unroll
      for (int j = 0; j < 8; j++) r8[j] = pc[dy * 20 + j];
      #pragma unroll
      for (int pr = 0; pr < 4; pr++) {
        const float4* kp = (const float4*)(s_kern + (((g * 4 + pr) * 25) + dy * 5) * 4);
        #pragma unroll
        for (int dx = 0; dx < 5; dx++) {
          float f = r8[pr + dx];
          float4 k4 = kp[dx];
          acc[pr][0] += f * k4.x;
          acc[pr][1] += f * k4.y;
          acc[pr][2] += f * k4.z;
          acc[pr][3] += f * k4.w;
        }
      }
    }
    __syncthreads();
    // transpose through LDS: s_out[c][x] stride 130, x = wl*8 + u*2 + hb
    #pragma unroll
    for (int pr = 0; pr < 4; pr++) {
      int wl = wl0 + pr;
      #pragma unroll
      for (int u = 0; u < 4; u++) {
        int xo = wl * 8 + u * 2 + hb;
        s_out[cl * 130 + xo] = acc[pr][u];
      }
    }
    __syncthreads();
    // coalesced store: 32 channel-rows x 128 x at fixed yout (plain stores:
    // L2 absorbs them in ~200cy so the next barrier's vmcnt drain is cheap)
    float* obase = out + ((size_t)(cbase + cc * 32) * 128 + yout) * 128;
    #pragma unroll
    for (int it = 0; it < 4; it++) {
      int q2 = t + it * 256;
      int rowc = q2 >> 5;       // 0..31 (channel within chunk)
      int col4 = q2 & 31;       // float4 index within row
      const float* sp = s_out + rowc * 130 + col4 * 4;
      float4 v = make_float4(sp[0], sp[1], sp[2], sp[3]);
      *(float4*)(obase + (size_t)rowc * (128 * 128) + col4 * 4) = v;
    }
  }
}

extern "C" void kernel_launch(void* const* d_in, const int* in_sizes, int n_in,
                              void* d_out, int out_size, void* d_ws, size_t ws_size,
                              hipStream_t stream) {
  const float* x      = (const float*)d_in[0];
  const float* w_comp = (const float*)d_in[1];
  const float* b_comp = (const float*)d_in[2];
  const float* w_ker  = (const float*)d_in[3];
  const float* b_ker  = (const float*)d_in[4];
  const float* w_off  = (const float*)d_in[5];
  const float* b_off  = (const float*)d_in[6];
  float* out = (float*)d_out;
  float* ws = (float*)d_ws;
  float* cx    = ws + WS_CX;
  float* offb  = ws + WS_OFF;
  float* maskb = ws + WS_MASK;
  float* wT    = ws + WS_WT;
  float* wcT   = ws + WS_MASK;   // temporal overlay: dead before k_convsm writes maskb

  hipLaunchKernelGGL(k_wt, dim3((NWT + NWC + 255) / 256), dim3(256), 0, stream,
                     w_ker, w_off, w_comp, wT, wcT);
  hipLaunchKernelGGL(k_compress, dim3(256), dim3(512), 0, stream, x, wcT, b_comp, cx);
  hipLaunchKernelGGL(k_convsm, dim3(64, 4), dim3(512), 0, stream,
                     cx, wT, b_ker, b_off, offb, maskb);
  hipLaunchKernelGGL(k_carafe, dim3(1024), dim3(256), 0, stream, x, offb, maskb, out);
}

// Round 5
// 183.070 us; speedup vs baseline: 1.1425x; 1.1425x over previous
//
#include <hip/hip_runtime.h>
#include <math.h>

#define NB 4
#define C_IN 256
#define CKC 64
#define HWSZ 4096   // 64*64
#define K2 25
#define NOC2 40     // 33 output chans padded to 40 (8 groups x 5)

// workspace layout (float offsets)
#define WS_CX    0
#define WS_OFF   (WS_CX + NB*CKC*HWSZ)          // 1048576
#define WS_MASK  (WS_OFF + NB*8*HWSZ)           // +131072
#define WS_WT    (WS_MASK + NB*K2*HWSZ)         // +409600
// wcT (16384 floats) overlays WS_MASK: dead until k_convsm writes maskb,
// and k_compress (its only reader) runs before k_convsm.

#define NWT (CKC * 9 * NOC2)    // 23040
#define NWC (C_IN * CKC)        // 16384

// ---------------- Kernel D: weight prep ----------------
// wT[c][tap][oc(40)] for the 3x3 convs; wcT[c][ck] for the compressor.
__global__ void k_wt(const float* __restrict__ wk, const float* __restrict__ wo,
                     const float* __restrict__ wc,
                     float* __restrict__ wT, float* __restrict__ wcT) {
  int i = blockIdx.x * 256 + threadIdx.x;
  if (i < NWT) {
    int oc = i % NOC2;
    int r = i / NOC2;        // r = c*9 + tap
    int tap = r % 9, c = r / 9;
    float v = 0.f;
    if (oc < 8)       v = wo[(oc * CKC + c) * 9 + tap];
    else if (oc < 33) v = wk[((oc - 8) * CKC + c) * 9 + tap];
    wT[i] = v;
  } else {
    int j = i - NWT;
    if (j < NWC) {
      int c = j >> 6, ck = j & 63;
      wcT[j] = wc[ck * C_IN + c];
    }
  }
}

// ---------------- Kernel A (v2): 1x1 compressor as LDS-tiled GEMM ----------
// 256 blocks x 512 thr; block = one 64-pixel row, 8 waves = 8 ck-groups of 8.
// x staged in LDS 64c-chunks; weights via wave-uniform s_load from wcT.
__global__ __launch_bounds__(512) void k_compress(const float* __restrict__ x,
    const float* __restrict__ wcT, const float* __restrict__ bc,
    float* __restrict__ cx) {
  __shared__ float s_x[64 * 64];   // [c][pos] 16KB
  int t = threadIdx.x;
  int pos0 = blockIdx.x * 64;
  int n = pos0 >> 12, hw0 = pos0 & 4095;
  int p = t & 63;
  int g = __builtin_amdgcn_readfirstlane(t >> 6);   // ck-group 0..7, wave-uniform
  const float* xn = x + (size_t)n * (C_IN * HWSZ) + hw0;
  float acc[8];
  #pragma unroll
  for (int i = 0; i < 8; i++) acc[i] = bc[g * 8 + i];
  for (int cc = 0; cc < 4; cc++) {
    __syncthreads();
    #pragma unroll
    for (int it = 0; it < 8; it++) {
      int idx = t + it * 512;
      int c = idx >> 6, pp = idx & 63;
      s_x[idx] = xn[(cc * 64 + c) * HWSZ + pp];
    }
    __syncthreads();
    const float* wbase = wcT + (cc * 64) * 64 + g * 8;
    #pragma unroll 4
    for (int c = 0; c < 64; c++) {
      float v = s_x[c * 64 + p];
      const float* w = wbase + c * 64;
      #pragma unroll
      for (int i = 0; i < 8; i++) acc[i] += v * w[i];
    }
  }
  float* o = cx + (size_t)n * (CKC * HWSZ) + hw0 + p;
  #pragma unroll
  for (int i = 0; i < 8; i++) o[(g * 8 + i) * HWSZ] = acc[i];
}

// ---------------- Kernel B (v3): fused 3x3 convs + softmax ----------------
// grid (64,4) x 512 thr: block = one 16x4 spatial tile; 64 px x 8 oc-groups
// of 5 (NOC2=40). 2 waves/SIMD for latency hiding.
__global__ __launch_bounds__(512) void k_convsm(const float* __restrict__ cx,
    const float* __restrict__ wT, const float* __restrict__ bk, const float* __restrict__ bo,
    float* __restrict__ offb, float* __restrict__ maskb) {
  __shared__ float s_tile[64 * 108];   // 64 c x (6 rows x 18 cols) halo tile
  __shared__ float s_res[NOC2 * 64];   // [oc][px]
  int t = threadIdx.x;
  int n = blockIdx.y;
  int tile = blockIdx.x;
  int x0 = (tile & 3) * 16, y0 = (tile >> 2) * 4;
  const float* cxn = cx + n * (CKC * HWSZ);

  // stage cx halo tile (zero-padded)
  for (int idx = t; idx < 6912; idx += 512) {
    int c = idx / 108;
    int rem = idx - c * 108;
    int row = rem / 18, col = rem - row * 18;
    int gy = y0 - 1 + row, gx = x0 - 1 + col;
    float v = 0.f;
    if ((unsigned)gy < 64u && (unsigned)gx < 64u) v = cxn[c * HWSZ + gy * 64 + gx];
    s_tile[idx] = v;
  }
  __syncthreads();

  int p = t & 63;
  int px = p & 15, py = p >> 4;
  int g = __builtin_amdgcn_readfirstlane(t >> 6);   // oc-group 0..7, wave-uniform
  float acc[5];
  #pragma unroll
  for (int j = 0; j < 5; j++) acc[j] = 0.f;
  const float* wg = wT + g * 5;
  for (int c = 0; c < CKC; c++) {
    const float* tl = s_tile + c * 108 + py * 18 + px;
    const float* wc9 = wg + c * 9 * NOC2;
    #pragma unroll
    for (int tap = 0; tap < 9; tap++) {
      int dy = tap / 3, dx = tap % 3;
      float v = tl[dy * 18 + dx];
      const float* w = wc9 + tap * NOC2;
      #pragma unroll
      for (int j = 0; j < 5; j++) acc[j] += v * w[j];
    }
  }
  #pragma unroll
  for (int j = 0; j < 5; j++) s_res[(g * 5 + j) * 64 + p] = acc[j];
  __syncthreads();

  int hw = (y0 + py) * 64 + x0 + px;
  // offsets: 8 channels; group g writes oc = g (row index == oc)
  offb[(n * 8 + g) * HWSZ + hw] = s_res[g * 64 + p] + bo[g];
  // softmax over 25 kernel positions: threads 0..63, one pixel per lane
  if (t < 64) {
    float m[25], mx = -1e30f;
    #pragma unroll
    for (int k = 0; k < 25; k++) { m[k] = s_res[(8 + k) * 64 + p] + bk[k]; mx = fmaxf(mx, m[k]); }
    float s = 0.f;
    #pragma unroll
    for (int k = 0; k < 25; k++) { m[k] = __expf(m[k] - mx); s += m[k]; }
    float inv = 1.f / s;
    #pragma unroll
    for (int k = 0; k < 25; k++) maskb[(n * 25 + k) * HWSZ + hw] = m[k] * inv;
  }
}

// ---------------- Kernel C (v6): main CARAFE reassembly ----------------
// 1024 blocks x 256 thr = 4 blocks/CU (LDS 38.7KB). Block = (n, a, wq, c-half).
// Structure = r1/v3 exactly (best measured 62.4us: register prefetch T14,
// plain stores, phase-1 on t<128, NO xcd swizzle -- r3/r4 showed swizzle
// optimizes FETCH, a non-binding constraint at 25% HBM, and costs time).
// v6: float2 patch staging. Old: 25 scattered 4B loads/thread/chunk = 64
//     L2 transactions per wave-load -> ~115K L2 requests/CU total ->
//     request-rate bound (the invisible limiter: all % counters < 35%).
//     New: rows are 20 consecutive floats at 8B-aligned col (16wq-2)*4,
//     so stage 13 float2 pairs/thread (halved request count). OOB pairs
//     are always fully-OOB (edge cols -2/-1 and 64/65), so per-pair
//     validity is exact. LDS stride 201->202 keeps 8B dst alignment;
//     cl*202 read pattern = 2-way bank aliasing = free. dst = 2*(e+c).
__global__ __launch_bounds__(256, 4) void k_carafe(const float* __restrict__ x,
    const float* __restrict__ offb, const float* __restrict__ maskb,
    float* __restrict__ out) {
  __attribute__((aligned(16))) __shared__ float s_patch[32 * 202]; // 25856B; aliased as s_out [32][130]
  __attribute__((aligned(16))) __shared__ float s_kern[32 * 25 * 4]; // 12800B
  int t = threadIdx.x;
  int b = blockIdx.x;
  int n = b >> 8;
  int r = b & 255;
  int half = r & 1;
  int wq = (r >> 1) & 3;
  int aa = r >> 3;
  int a = aa + (aa & 16);                 // h base: bit4 == 0
  int yout = (a & 15) * 8 + wq * 2 + ((a >> 5) & 1);
  int w0 = wq * 16;
  int cbase = n * C_IN + half * 128;

  // ---- hoisted float2 staging descriptors (computed ONCE) ----
  // pair e = t + it*256 over 3200 = 32c x (10 rows x 10 float2); within a
  // channel, float offset = 2*rem -> dst = c*202 + 2*rem = 2*(e + c).
  int srcOff[13];          // channel-plane-relative src offset (pair base)
  int dstOff[13];          // LDS float index (8B aligned)
  unsigned vbits = 0;      // data-valid (in-bounds) mask
  unsigned wbits = 0;      // write-enable (e < 3200) mask
  #pragma unroll
  for (int it = 0; it < 13; it++) {
    int e = t + it * 256;
    int c = e / 100;
    int rem = e - c * 100;
    int rg = rem / 10;
    int c2 = rem - rg * 10;
    int row = (rg < 5) ? (a - 2 + rg) : (a + 9 + rg);
    int gc0 = w0 - 2 + c2 * 2;
    bool wr = (e < 3200);
    bool ok = wr & ((unsigned)row < 64u) & ((unsigned)gc0 < 64u);
    srcOff[it] = ok ? (c * HWSZ + row * 64 + gc0) : 0;
    dstOff[it] = wr ? 2 * (e + c) : 0;
    vbits |= (ok ? 1u : 0u) << it;
    wbits |= (wr ? 1u : 0u) << it;
  }

  // prefetch chunk 0 into registers (flies during phase 1)
  float2 rv[13];
  {
    const float* xn = x + (size_t)cbase * HWSZ;
    #pragma unroll
    for (int it = 0; it < 13; it++) rv[it] = *(const float2*)(xn + srcOff[it]);
  }

  // Phase 1: per-(pos,u) 25 resampled kernel weights -> LDS [p][tap][u]
  if (t < 128) {
    int p = t >> 2, u = t & 3;
    int hb = p >> 4, wl = p & 15;
    int h = a + hb * 16;
    int wcol = w0 + wl;
    float ox = offb[(n * 8 + u) * HWSZ + h * 64 + wcol];
    float oy = offb[(n * 8 + 4 + u) * HWSZ + h * 64 + wcol];
    float gx = fminf(fmaxf((float)wcol + ox, 0.f), 63.f);
    float gy = fminf(fmaxf((float)h + oy, 0.f), 63.f);
    float fx0 = floorf(gx), fy0 = floorf(gy);
    int x0 = (int)fx0, y0 = (int)fy0;
    float fx = gx - fx0, fy = gy - fy0;
    int x1 = min(x0 + 1, 63), y1 = min(y0 + 1, 63);
    float w11 = fx * fy;
    float w10 = fy - w11, w01 = fx - w11, w00 = 1.f - fx - fy + w11;
    const float* mb = maskb + n * (K2 * HWSZ);
    int i00 = y0 * 64 + x0, i01 = y0 * 64 + x1;
    int i10 = y1 * 64 + x0, i11 = y1 * 64 + x1;
    #pragma unroll 5
    for (int k = 0; k < 25; k++) {
      const float* mk = mb + k * HWSZ;
      float v = w00 * mk[i00] + w01 * mk[i01] + w10 * mk[i10] + w11 * mk[i11];
      s_kern[(p * 25 + k) * 4 + u] = v;
    }
  }

  int cl = t & 31, g = t >> 5;            // channel lane 0..31, pos-group 0..7
  int hb = g >> 2, wl0 = (g & 3) * 4;     // each group: 4 consecutive wl in one hb
  float* s_out = s_patch;                 // alias: [32][130] = 16640B <= 25856B

  for (int cc = 0; cc < 4; cc++) {
    __syncthreads();   // covers phase-1 (first iter) and staging-vs-store alias (later)
    // stage x patch from prefetched registers: 32 c x 10 rows x 20 cols
    #pragma unroll
    for (int it = 0; it < 13; it++) {
      if (wbits & (1u << it)) {
        float2 v = (vbits & (1u << it)) ? rv[it] : make_float2(0.f, 0.f);
        *(float2*)(&s_patch[dstOff[it]]) = v;   // ds_write_b64
      }
    }
    __syncthreads();
    // issue next chunk's loads NOW; latency hides under compute+store below
    if (cc < 3) {
      const float* xn = x + (size_t)(cbase + (cc + 1) * 32) * HWSZ;
      #pragma unroll
      for (int it = 0; it < 13; it++) rv[it] = *(const float2*)(xn + srcOff[it]);
    }
    // compute: thread (cl, g) -> 4 positions x 4 u; register row-cache over dy
    float acc[4][4];
    #pragma unroll
    for (int i = 0; i < 4; i++)
      acc[i][0] = acc[i][1] = acc[i][2] = acc[i][3] = 0.f;
    const float* pc = s_patch + cl * 202 + hb * 100 + wl0;
    #pragma unroll
    for (int dy = 0; dy < 5; dy++) {
      float r8[8];
      #pragma unroll
      for (int j = 0; j < 8; j++) r8[j] = pc[dy * 20 + j];
      #pragma unroll
      for (int pr = 0; pr < 4; pr++) {
        const float4* kp = (const float4*)(s_kern + (((g * 4 + pr) * 25) + dy * 5) * 4);
        #pragma unroll
        for (int dx = 0; dx < 5; dx++) {
          float f = r8[pr + dx];
          float4 k4 = kp[dx];
          acc[pr][0] += f * k4.x;
          acc[pr][1] += f * k4.y;
          acc[pr][2] += f * k4.z;
          acc[pr][3] += f * k4.w;
        }
      }
    }
    __syncthreads();
    // transpose through LDS: s_out[c][x] stride 130, x = wl*8 + u*2 + hb
    #pragma unroll
    for (int pr = 0; pr < 4; pr++) {
      int wl = wl0 + pr;
      #pragma unroll
      for (int u = 0; u < 4; u++) {
        int xo = wl * 8 + u * 2 + hb;
        s_out[cl * 130 + xo] = acc[pr][u];
      }
    }
    __syncthreads();
    // coalesced store: 32 channel-rows x 128 x at fixed yout
    float* obase = out + ((size_t)(cbase + cc * 32) * 128 + yout) * 128;
    #pragma unroll
    for (int it = 0; it < 4; it++) {
      int q2 = t + it * 256;
      int rowc = q2 >> 5;       // 0..31 (channel within chunk)
      int col4 = q2 & 31;       // float4 index within row
      const float* sp = s_out + rowc * 130 + col4 * 4;
      float4 v = make_float4(sp[0], sp[1], sp[2], sp[3]);
      *(float4*)(obase + (size_t)rowc * (128 * 128) + col4 * 4) = v;
    }
  }
}

extern "C" void kernel_launch(void* const* d_in, const int* in_sizes, int n_in,
                              void* d_out, int out_size, void* d_ws, size_t ws_size,
                              hipStream_t stream) {
  const float* x      = (const float*)d_in[0];
  const float* w_comp = (const float*)d_in[1];
  const float* b_comp = (const float*)d_in[2];
  const float* w_ker  = (const float*)d_in[3];
  const float* b_ker  = (const float*)d_in[4];
  const float* w_off  = (const float*)d_in[5];
  const float* b_off  = (const float*)d_in[6];
  float* out = (float*)d_out;
  float* ws = (float*)d_ws;
  float* cx    = ws + WS_CX;
  float* offb  = ws + WS_OFF;
  float* maskb = ws + WS_MASK;
  float* wT    = ws + WS_WT;
  float* wcT   = ws + WS_MASK;   // temporal overlay: dead before k_convsm writes maskb

  hipLaunchKernelGGL(k_wt, dim3((NWT + NWC + 255) / 256), dim3(256), 0, stream,
                     w_ker, w_off, w_comp, wT, wcT);
  hipLaunchKernelGGL(k_compress, dim3(256), dim3(512), 0, stream, x, wcT, b_comp, cx);
  hipLaunchKernelGGL(k_convsm, dim3(64, 4), dim3(512), 0, stream,
                     cx, wT, b_ker, b_off, offb, maskb);
  hipLaunchKernelGGL(k_carafe, dim3(1024), dim3(256), 0, stream, x, offb, maskb, out);
}

// Round 6
// 181.247 us; speedup vs baseline: 1.1540x; 1.0101x over previous
//
#include <hip/hip_runtime.h>
#include <math.h>

#define NB 4
#define C_IN 256
#define CKC 64
#define HWSZ 4096   // 64*64
#define K2 25
#define NOC2 40     // 33 output chans padded to 40 (8 groups x 5)

// workspace layout (float offsets)
#define WS_CX    0
#define WS_OFF   (WS_CX + NB*CKC*HWSZ)          // 1048576
#define WS_MASK  (WS_OFF + NB*8*HWSZ)           // +131072
#define WS_WT    (WS_MASK + NB*K2*HWSZ)         // +409600
// wcT (16384 floats) overlays WS_MASK: dead until k_convsm writes maskb,
// and k_compress (its only reader) runs before k_convsm.

#define NWT (CKC * 9 * NOC2)    // 23040
#define NWC (C_IN * CKC)        // 16384

// ---------------- Kernel D: weight prep ----------------
// wT[c][tap][oc(40)] for the 3x3 convs; wcT[c][ck] for the compressor.
__global__ void k_wt(const float* __restrict__ wk, const float* __restrict__ wo,
                     const float* __restrict__ wc,
                     float* __restrict__ wT, float* __restrict__ wcT) {
  int i = blockIdx.x * 256 + threadIdx.x;
  if (i < NWT) {
    int oc = i % NOC2;
    int r = i / NOC2;        // r = c*9 + tap
    int tap = r % 9, c = r / 9;
    float v = 0.f;
    if (oc < 8)       v = wo[(oc * CKC + c) * 9 + tap];
    else if (oc < 33) v = wk[((oc - 8) * CKC + c) * 9 + tap];
    wT[i] = v;
  } else {
    int j = i - NWT;
    if (j < NWC) {
      int c = j >> 6, ck = j & 63;
      wcT[j] = wc[ck * C_IN + c];
    }
  }
}

// ---------------- Kernel A (v3): 1x1 compressor as LDS-tiled GEMM ----------
// 256 blocks x 512 thr; block = one 64-pixel row, 8 waves = 8 ck-groups of 8.
// v3: T14 cross-chunk register prefetch -- chunk cc+1's 8 staging loads are
// issued right after the post-staging barrier, so their HBM/L2 latency hides
// under chunk cc's 512-FMA compute phase instead of being exposed between
// the barrier pair (same pattern that cut k_carafe 66.8->62.4 in r1).
__global__ __launch_bounds__(512) void k_compress(const float* __restrict__ x,
    const float* __restrict__ wcT, const float* __restrict__ bc,
    float* __restrict__ cx) {
  __shared__ float s_x[64 * 64];   // [c][pos] 16KB
  int t = threadIdx.x;
  int pos0 = blockIdx.x * 64;
  int n = pos0 >> 12, hw0 = pos0 & 4095;
  int p = t & 63;
  int g = __builtin_amdgcn_readfirstlane(t >> 6);   // ck-group 0..7, wave-uniform
  const float* xn = x + (size_t)n * (C_IN * HWSZ) + hw0;
  float acc[8];
  #pragma unroll
  for (int i = 0; i < 8; i++) acc[i] = bc[g * 8 + i];

  // prefetch chunk 0 into registers
  float rv[8];
  #pragma unroll
  for (int it = 0; it < 8; it++) {
    int idx = t + it * 512;
    int c = idx >> 6, pp = idx & 63;
    rv[it] = xn[c * HWSZ + pp];
  }

  for (int cc = 0; cc < 4; cc++) {
    __syncthreads();
    #pragma unroll
    for (int it = 0; it < 8; it++) s_x[t + it * 512] = rv[it];
    __syncthreads();
    // issue next chunk's loads NOW; latency hides under the FMA phase
    if (cc < 3) {
      #pragma unroll
      for (int it = 0; it < 8; it++) {
        int idx = t + it * 512;
        int c = idx >> 6, pp = idx & 63;
        rv[it] = xn[((cc + 1) * 64 + c) * HWSZ + pp];
      }
    }
    const float* wbase = wcT + (cc * 64) * 64 + g * 8;
    #pragma unroll 4
    for (int c = 0; c < 64; c++) {
      float v = s_x[c * 64 + p];
      const float* w = wbase + c * 64;
      #pragma unroll
      for (int i = 0; i < 8; i++) acc[i] += v * w[i];
    }
  }
  float* o = cx + (size_t)n * (CKC * HWSZ) + hw0 + p;
  #pragma unroll
  for (int i = 0; i < 8; i++) o[(g * 8 + i) * HWSZ] = acc[i];
}

// ---------------- Kernel B (v4): fused 3x3 convs + softmax ----------------
// grid (64,4) x 512 thr: block = one 16x4 spatial tile; 64 px x 8 oc-groups
// of 5 (NOC2=40). 2 waves/SIMD for latency hiding.
// v4: explicit 2-deep software pipeline of the c-loop: double-buffered
// 9-value window registers (named wa/wb -- static indexing, no scratch) so
// channel c+2's 9 ds_reads are in flight during c+1's 45 FMAs, instead of
// a dependent ds_read->FMA chain per channel.
__global__ __launch_bounds__(512) void k_convsm(const float* __restrict__ cx,
    const float* __restrict__ wT, const float* __restrict__ bk, const float* __restrict__ bo,
    float* __restrict__ offb, float* __restrict__ maskb) {
  __shared__ float s_tile[64 * 108];   // 64 c x (6 rows x 18 cols) halo tile
  __shared__ float s_res[NOC2 * 64];   // [oc][px]
  int t = threadIdx.x;
  int n = blockIdx.y;
  int tile = blockIdx.x;
  int x0 = (tile & 3) * 16, y0 = (tile >> 2) * 4;
  const float* cxn = cx + n * (CKC * HWSZ);

  // stage cx halo tile (zero-padded)
  for (int idx = t; idx < 6912; idx += 512) {
    int c = idx / 108;
    int rem = idx - c * 108;
    int row = rem / 18, col = rem - row * 18;
    int gy = y0 - 1 + row, gx = x0 - 1 + col;
    float v = 0.f;
    if ((unsigned)gy < 64u && (unsigned)gx < 64u) v = cxn[c * HWSZ + gy * 64 + gx];
    s_tile[idx] = v;
  }
  __syncthreads();

  int p = t & 63;
  int px = p & 15, py = p >> 4;
  int g = __builtin_amdgcn_readfirstlane(t >> 6);   // oc-group 0..7, wave-uniform
  float acc[5];
  #pragma unroll
  for (int j = 0; j < 5; j++) acc[j] = 0.f;
  const float* wg = wT + g * 5;
  const float* tl0 = s_tile + py * 18 + px;

#define LOADWIN(dst, cidx)                                   \
  {                                                          \
    const float* tlc = tl0 + (cidx) * 108;                   \
    _Pragma("unroll")                                        \
    for (int tap = 0; tap < 9; tap++) {                      \
      int dy = tap / 3, dx = tap % 3;                        \
      dst[tap] = tlc[dy * 18 + dx];                          \
    }                                                        \
  }
#define FMAWIN(src, cidx)                                    \
  {                                                          \
    const float* wc9 = wg + (cidx) * 9 * NOC2;               \
    _Pragma("unroll")                                        \
    for (int tap = 0; tap < 9; tap++) {                      \
      float v = src[tap];                                    \
      const float* w = wc9 + tap * NOC2;                     \
      _Pragma("unroll")                                      \
      for (int j = 0; j < 5; j++) acc[j] += v * w[j];        \
    }                                                        \
  }

  float wa[9], wb[9];
  LOADWIN(wa, 0)
  LOADWIN(wb, 1)
  #pragma unroll 1
  for (int c = 0; c < CKC; c += 2) {
    FMAWIN(wa, c)
    if (c + 2 < CKC) LOADWIN(wa, c + 2)
    FMAWIN(wb, c + 1)
    if (c + 3 < CKC) LOADWIN(wb, c + 3)
  }
#undef LOADWIN
#undef FMAWIN

  #pragma unroll
  for (int j = 0; j < 5; j++) s_res[(g * 5 + j) * 64 + p] = acc[j];
  __syncthreads();

  int hw = (y0 + py) * 64 + x0 + px;
  // offsets: 8 channels; group g writes oc = g (row index == oc)
  offb[(n * 8 + g) * HWSZ + hw] = s_res[g * 64 + p] + bo[g];
  // softmax over 25 kernel positions: threads 0..63, one pixel per lane
  if (t < 64) {
    float m[25], mx = -1e30f;
    #pragma unroll
    for (int k = 0; k < 25; k++) { m[k] = s_res[(8 + k) * 64 + p] + bk[k]; mx = fmaxf(mx, m[k]); }
    float s = 0.f;
    #pragma unroll
    for (int k = 0; k < 25; k++) { m[k] = __expf(m[k] - mx); s += m[k]; }
    float inv = 1.f / s;
    #pragma unroll
    for (int k = 0; k < 25; k++) maskb[(n * 25 + k) * HWSZ + hw] = m[k] * inv;
  }
}

// ---------------- Kernel C (v6): main CARAFE reassembly ----------------
// FROZEN at r5's 45.1us version (float2 staging, T14 prefetch, plain stores,
// no swizzle). See r5 notes: request-rate theory confirmed (62.4 -> 45.1).
__global__ __launch_bounds__(256, 4) void k_carafe(const float* __restrict__ x,
    const float* __restrict__ offb, const float* __restrict__ maskb,
    float* __restrict__ out) {
  __attribute__((aligned(16))) __shared__ float s_patch[32 * 202]; // 25856B; aliased as s_out [32][130]
  __attribute__((aligned(16))) __shared__ float s_kern[32 * 25 * 4]; // 12800B
  int t = threadIdx.x;
  int b = blockIdx.x;
  int n = b >> 8;
  int r = b & 255;
  int half = r & 1;
  int wq = (r >> 1) & 3;
  int aa = r >> 3;
  int a = aa + (aa & 16);                 // h base: bit4 == 0
  int yout = (a & 15) * 8 + wq * 2 + ((a >> 5) & 1);
  int w0 = wq * 16;
  int cbase = n * C_IN + half * 128;

  // ---- hoisted float2 staging descriptors (computed ONCE) ----
  int srcOff[13];          // channel-plane-relative src offset (pair base)
  int dstOff[13];          // LDS float index (8B aligned)
  unsigned vbits = 0;      // data-valid (in-bounds) mask
  unsigned wbits = 0;      // write-enable (e < 3200) mask
  #pragma unroll
  for (int it = 0; it < 13; it++) {
    int e = t + it * 256;
    int c = e / 100;
    int rem = e - c * 100;
    int rg = rem / 10;
    int c2 = rem - rg * 10;
    int row = (rg < 5) ? (a - 2 + rg) : (a + 9 + rg);
    int gc0 = w0 - 2 + c2 * 2;
    bool wr = (e < 3200);
    bool ok = wr & ((unsigned)row < 64u) & ((unsigned)gc0 < 64u);
    srcOff[it] = ok ? (c * HWSZ + row * 64 + gc0) : 0;
    dstOff[it] = wr ? 2 * (e + c) : 0;
    vbits |= (ok ? 1u : 0u) << it;
    wbits |= (wr ? 1u : 0u) << it;
  }

  // prefetch chunk 0 into registers (flies during phase 1)
  float2 rv[13];
  {
    const float* xn = x + (size_t)cbase * HWSZ;
    #pragma unroll
    for (int it = 0; it < 13; it++) rv[it] = *(const float2*)(xn + srcOff[it]);
  }

  // Phase 1: per-(pos,u) 25 resampled kernel weights -> LDS [p][tap][u]
  if (t < 128) {
    int p = t >> 2, u = t & 3;
    int hb = p >> 4, wl = p & 15;
    int h = a + hb * 16;
    int wcol = w0 + wl;
    float ox = offb[(n * 8 + u) * HWSZ + h * 64 + wcol];
    float oy = offb[(n * 8 + 4 + u) * HWSZ + h * 64 + wcol];
    float gx = fminf(fmaxf((float)wcol + ox, 0.f), 63.f);
    float gy = fminf(fmaxf((float)h + oy, 0.f), 63.f);
    float fx0 = floorf(gx), fy0 = floorf(gy);
    int x0 = (int)fx0, y0 = (int)fy0;
    float fx = gx - fx0, fy = gy - fy0;
    int x1 = min(x0 + 1, 63), y1 = min(y0 + 1, 63);
    float w11 = fx * fy;
    float w10 = fy - w11, w01 = fx - w11, w00 = 1.f - fx - fy + w11;
    const float* mb = maskb + n * (K2 * HWSZ);
    int i00 = y0 * 64 + x0, i01 = y0 * 64 + x1;
    int i10 = y1 * 64 + x0, i11 = y1 * 64 + x1;
    #pragma unroll 5
    for (int k = 0; k < 25; k++) {
      const float* mk = mb + k * HWSZ;
      float v = w00 * mk[i00] + w01 * mk[i01] + w10 * mk[i10] + w11 * mk[i11];
      s_kern[(p * 25 + k) * 4 + u] = v;
    }
  }

  int cl = t & 31, g = t >> 5;            // channel lane 0..31, pos-group 0..7
  int hb = g >> 2, wl0 = (g & 3) * 4;     // each group: 4 consecutive wl in one hb
  float* s_out = s_patch;                 // alias: [32][130] = 16640B <= 25856B

  for (int cc = 0; cc < 4; cc++) {
    __syncthreads();   // covers phase-1 (first iter) and staging-vs-store alias (later)
    // stage x patch from prefetched registers: 32 c x 10 rows x 20 cols
    #pragma unroll
    for (int it = 0; it < 13; it++) {
      if (wbits & (1u << it)) {
        float2 v = (vbits & (1u << it)) ? rv[it] : make_float2(0.f, 0.f);
        *(float2*)(&s_patch[dstOff[it]]) = v;   // ds_write_b64
      }
    }
    __syncthreads();
    // issue next chunk's loads NOW; latency hides under compute+store below
    if (cc < 3) {
      const float* xn = x + (size_t)(cbase + (cc + 1) * 32) * HWSZ;
      #pragma unroll
      for (int it = 0; it < 13; it++) rv[it] = *(const float2*)(xn + srcOff[it]);
    }
    // compute: thread (cl, g) -> 4 positions x 4 u; register row-cache over dy
    float acc[4][4];
    #pragma unroll
    for (int i = 0; i < 4; i++)
      acc[i][0] = acc[i][1] = acc[i][2] = acc[i][3] = 0.f;
    const float* pc = s_patch + cl * 202 + hb * 100 + wl0;
    #pragma unroll
    for (int dy = 0; dy < 5; dy++) {
      float r8[8];
      #pragma unroll
      for (int j = 0; j < 8; j++) r8[j] = pc[dy * 20 + j];
      #pragma unroll
      for (int pr = 0; pr < 4; pr++) {
        const float4* kp = (const float4*)(s_kern + (((g * 4 + pr) * 25) + dy * 5) * 4);
        #pragma unroll
        for (int dx = 0; dx < 5; dx++) {
          float f = r8[pr + dx];
          float4 k4 = kp[dx];
          acc[pr][0] += f * k4.x;
          acc[pr][1] += f * k4.y;
          acc[pr][2] += f * k4.z;
          acc[pr][3] += f * k4.w;
        }
      }
    }
    __syncthreads();
    // transpose through LDS: s_out[c][x] stride 130, x = wl*8 + u*2 + hb
    #pragma unroll
    for (int pr = 0; pr < 4; pr++) {
      int wl = wl0 + pr;
      #pragma unroll
      for (int u = 0; u < 4; u++) {
        int xo = wl * 8 + u * 2 + hb;
        s_out[cl * 130 + xo] = acc[pr][u];
      }
    }
    __syncthreads();
    // coalesced store: 32 channel-rows x 128 x at fixed yout
    float* obase = out + ((size_t)(cbase + cc * 32) * 128 + yout) * 128;
    #pragma unroll
    for (int it = 0; it < 4; it++) {
      int q2 = t + it * 256;
      int rowc = q2 >> 5;       // 0..31 (channel within chunk)
      int col4 = q2 & 31;       // float4 index within row
      const float* sp = s_out + rowc * 130 + col4 * 4;
      float4 v = make_float4(sp[0], sp[1], sp[2], sp[3]);
      *(float4*)(obase + (size_t)rowc * (128 * 128) + col4 * 4) = v;
    }
  }
}

extern "C" void kernel_launch(void* const* d_in, const int* in_sizes, int n_in,
                              void* d_out, int out_size, void* d_ws, size_t ws_size,
                              hipStream_t stream) {
  const float* x      = (const float*)d_in[0];
  const float* w_comp = (const float*)d_in[1];
  const float* b_comp = (const float*)d_in[2];
  const float* w_ker  = (const float*)d_in[3];
  const float* b_ker  = (const float*)d_in[4];
  const float* w_off  = (const float*)d_in[5];
  const float* b_off  = (const float*)d_in[6];
  float* out = (float*)d_out;
  float* ws = (float*)d_ws;
  float* cx    = ws + WS_CX;
  float* offb  = ws + WS_OFF;
  float* maskb = ws + WS_MASK;
  float* wT    = ws + WS_WT;
  float* wcT   = ws + WS_MASK;   // temporal overlay: dead before k_convsm writes maskb

  hipLaunchKernelGGL(k_wt, dim3((NWT + NWC + 255) / 256), dim3(256), 0, stream,
                     w_ker, w_off, w_comp, wT, wcT);
  hipLaunchKernelGGL(k_compress, dim3(256), dim3(512), 0, stream, x, wcT, b_comp, cx);
  hipLaunchKernelGGL(k_convsm, dim3(64, 4), dim3(512), 0, stream,
                     cx, wT, b_ker, b_off, offb, maskb);
  hipLaunchKernelGGL(k_carafe, dim3(1024), dim3(256), 0, stream, x, offb, maskb, out);
}